// Round 3
// baseline (513.735 us; speedup 1.0000x reference)
//
#include <hip/hip_runtime.h>
#include <hip/hip_bf16.h>
#include <hip/hip_cooperative_groups.h>

namespace cg = cooperative_groups;

// ContactLoss: Möller–Trumbore parity ray-cast (x2) + nearest-neighbor anchors
// + masked tanh means. All fp32, fp-contract OFF to bit-match numpy reference.
//
// R3: single cooperative kernel (1 dispatch). phase0 {zero hits, tri_pre} |
// grid.sync | phase1 {raycast virtual blocks, then argmin waves} | grid.sync |
// phase2 {per-batch reduce} | grid.sync | finalize. Pass-A skips invalid points.

#define RX 0.4395064455f
#define RY 0.617598629942f
#define RZ 0.652231566745f

#define MAXCHUNK_F4 512   // LDS float4 slots; >= max(chunkA,chunkB)*4

struct Params {
    const float* hand_verts; const int* hand_faces;
    const float* obj_verts;  const int* obj_faces;
    const int* ovsplit; const int* ofsplit;
    float4* htri; float4* otri;
    int* hits;                 // [B*No] obj hits, then [B*Nh] hand hits
    float* anchor_h; float* anchor_o; float* partials;
    float* out;
    int B, Nh, Fh, No, Fo;
    int pbA, CA, chunkA, blocksA;
    int pbB, CB, chunkB, blocksB;
};

// ---------------------------------------------------------------------------
__device__ __forceinline__ void tri_pre_one(const float* __restrict__ vb,
                                            const int* __restrict__ f,
                                            bool split_ok, float4* __restrict__ o) {
#pragma clang fp contract(off)
    int i0 = f[0], i1 = f[1], i2 = f[2];
    float v0x = vb[i0*3+0], v0y = vb[i0*3+1], v0z = vb[i0*3+2];
    float v1x = vb[i1*3+0], v1y = vb[i1*3+1], v1z = vb[i1*3+2];
    float v2x = vb[i2*3+0], v2y = vb[i2*3+1], v2z = vb[i2*3+2];
    float e1x = v1x - v0x, e1y = v1y - v0y, e1z = v1z - v0z;
    float e2x = v2x - v0x, e2y = v2y - v0y, e2z = v2z - v0z;
    float px = RY*e2z - RZ*e2y;
    float py = RZ*e2x - RX*e2z;
    float pz = RX*e2y - RY*e2x;
    float det = (e1x*px + e1y*py) + e1z*pz;       // ((a+b)+c) like np.sum
    float invdet = 1.0f / (det + 1e-8f);          // 0.1*TOL, IEEE div
    bool valid = !(fabsf(det) < 1e-7f) && split_ok;
    o[0] = make_float4(v0x, v0y, v0z, invdet);
    o[1] = make_float4(e1x, e1y, e1z, valid ? 1.0f : 0.0f);
    o[2] = make_float4(e2x, e2y, e2z, 0.0f);
    o[3] = make_float4(px,  py,  pz,  0.0f);
}

// ---------------------------------------------------------------------------
// One virtual raycast block. Block-uniform early-outs; two block-local
// barriers per chunk (leading barrier protects LDS from the previous chunk).
// ---------------------------------------------------------------------------
__device__ __forceinline__ void raycast_vb(const Params& p, int vb, int tid,
                                           float4* s_tri) {
#pragma clang fp contract(off)
    const float* pts; const float4* tri; int* hits;
    int P, T, c, pb, b, chunk, tlim, plim;
    if (vb < p.blocksA) {
        int per_b = p.pbA * p.CA;
        b  = vb / per_b;
        int r = vb - b * per_b;
        c  = r / p.pbA;
        pb = r - c * p.pbA;
        pts = p.obj_verts; tri = p.htri; hits = p.hits;
        P = p.No; T = p.Fh; chunk = p.chunkA;
        tlim = p.Fh; plim = min(p.No, p.ovsplit[b]);   // invalid pts unused
    } else {
        int j = vb - p.blocksA;
        int per_b = p.pbB * p.CB;
        b  = j / per_b;
        int r = j - b * per_b;
        c  = r / p.pbB;
        pb = r - c * p.pbB;
        pts = p.hand_verts; tri = p.otri; hits = p.hits + (size_t)p.B * p.No;
        P = p.Nh; T = p.Fo; chunk = p.chunkB;
        tlim = min(p.Fo, p.ofsplit[b]); plim = p.Nh;
    }

    int tStart = c * chunk;
    if (tStart >= tlim) return;           // block-uniform
    if (pb * 256 >= plim) return;         // block-uniform
    int nTri = min(tStart + chunk, tlim) - tStart;

    __syncthreads();                      // previous chunk's readers done
    const float4* src = tri + ((size_t)b * T + tStart) * 4;
    int n4 = nTri * 4;
    for (int j = tid; j < n4; j += 256) s_tri[j] = src[j];

    int pp = pb * 256 + tid;
    bool act = pp < plim;
    float qx = 0.f, qy = 0.f, qz = 0.f;
    if (act) {
        const float* q = pts + ((size_t)b * P + pp) * 3;
        qx = q[0]; qy = q[1]; qz = q[2];
    }
    __syncthreads();

    if (act) {
        int cnt = 0;
        for (int i = 0; i < nTri; ++i) {
            const float4 f0 = s_tri[(i<<2)+0];
            const float4 f1 = s_tri[(i<<2)+1];
            const float4 f2 = s_tri[(i<<2)+2];
            const float4 f3 = s_tri[(i<<2)+3];
            float tvx = qx - f0.x, tvy = qy - f0.y, tvz = qz - f0.z;
            float u  = ((tvx*f3.x + tvy*f3.y) + tvz*f3.z) * f0.w;
            float qvx = tvy*f1.z - tvz*f1.y;
            float qvy = tvz*f1.x - tvx*f1.z;
            float qvz = tvx*f1.y - tvy*f1.x;
            float v  = ((qvx*RX + qvy*RY) + qvz*RZ) * f0.w;
            float tt = ((f2.x*qvx + f2.y*qvy) + f2.z*qvz) * f0.w;
            bool hit = (u > 0.0f) && (u < 1.0f) && (v > 0.0f) &&
                       ((u + v) < 1.0f) && (tt > 1e-7f) && (f1.w != 0.0f);
            cnt += hit ? 1 : 0;
        }
        if (cnt) atomicAdd(&hits[(size_t)b * P + pp], cnt);
    }
}

// ---------------------------------------------------------------------------
// One argmin wave. Packed (dist<<32)|idx min => np.argmin tie-break.
// ---------------------------------------------------------------------------
__device__ __forceinline__ void min_one(const Params& p, int w, int lane) {
#pragma clang fp contract(off)
    int nHand = p.B * p.Nh;
    const float* refv; const float* loopv; int loopN; float* outp;
    if (w < nHand) {
        int b = w / p.Nh;
        int n = w - b * p.Nh;
        refv  = p.hand_verts + ((size_t)b * p.Nh + n) * 3;
        loopv = p.obj_verts + (size_t)b * p.No * 3;
        loopN = p.ovsplit[b];
        outp  = p.anchor_h + (size_t)b * p.Nh + n;
    } else {
        int j = w - nHand;
        int b = j / p.No;
        int m = j - b * p.No;
        if (m >= p.ovsplit[b]) return;
        refv  = p.obj_verts + ((size_t)b * p.No + m) * 3;
        loopv = p.hand_verts + (size_t)b * p.Nh * 3;
        loopN = p.Nh;
        outp  = p.anchor_o + (size_t)b * p.No + m;
    }
    float hx = refv[0], hy = refv[1], hz = refv[2];
    float rx = (hx*hx + hy*hy) + hz*hz;
    unsigned long long best = ~0ull;
    for (int m = lane; m < loopN; m += 64) {
        float ox = loopv[m*3+0], oy = loopv[m*3+1], oz = loopv[m*3+2];
        float ry = (ox*ox + oy*oy) + oz*oz;
        float zz = (hx*ox + hy*oy) + hz*oz;
        float d = (rx + ry) - 2.0f * zz;
        unsigned long long e = ((unsigned long long)__float_as_uint(d) << 32) | (unsigned)m;
        if (e < best) best = e;
    }
    for (int off = 32; off > 0; off >>= 1) {
        unsigned long long o = __shfl_xor(best, off, 64);
        if (o < best) best = o;
    }
    if (lane == 0) {
        int idx = (best == ~0ull) ? 0 : (int)(best & 0xffffffffu);
        const float* cv = loopv + (size_t)idx * 3;
        float dx = cv[0] - hx, dy = cv[1] - hy, dz = cv[2] - hz;
        *outp = sqrtf((dx*dx + dy*dy) + dz*dz);
    }
}

// ---------------------------------------------------------------------------
// Per-batch masked sums (block b handles batch b), via wave shuffles + LDS.
// ---------------------------------------------------------------------------
__device__ __forceinline__ void reduce_batch_one(const Params& p, int b, int tid,
                                                 float* red) {
    int wave = tid >> 6, lane = tid & 63;
    const int* hits_obj  = p.hits;
    const int* hits_hand = p.hits + (size_t)p.B * p.No;
    float s0=0.f,s1=0.f,s2=0.f,s3=0.f,s4=0.f,s5=0.f;
    for (int n = tid; n < p.Nh; n += 256) {
        bool ext = (hits_hand[(size_t)b*p.Nh + n] & 1) == 0;
        float val = 25.0f * tanhf(p.anchor_h[(size_t)b*p.Nh + n] / 25.0f);
        if (ext) { s0 += val; s1 += 1.0f; } else { s2 += val; s3 += 1.0f; }
    }
    int split = p.ovsplit[b];
    for (int m = tid; m < split; m += 256) {
        if ((hits_obj[(size_t)b*p.No + m] & 1) != 0) {   // interior & valid
            s4 += 25.0f * tanhf(p.anchor_o[(size_t)b*p.No + m] / 25.0f);
            s5 += 1.0f;
        }
    }
    for (int off = 32; off > 0; off >>= 1) {
        s0 += __shfl_xor(s0, off, 64);
        s1 += __shfl_xor(s1, off, 64);
        s2 += __shfl_xor(s2, off, 64);
        s3 += __shfl_xor(s3, off, 64);
        s4 += __shfl_xor(s4, off, 64);
        s5 += __shfl_xor(s5, off, 64);
    }
    if (lane == 0) {
        red[wave*6+0]=s0; red[wave*6+1]=s1; red[wave*6+2]=s2;
        red[wave*6+3]=s3; red[wave*6+4]=s4; red[wave*6+5]=s5;
    }
    __syncthreads();
    if (tid == 0) {
        float t0=0.f,t1=0.f,t2=0.f,t3=0.f,t4=0.f,t5=0.f;
        for (int wv = 0; wv < 4; ++wv) {
            t0 += red[wv*6+0]; t1 += red[wv*6+1]; t2 += red[wv*6+2];
            t3 += red[wv*6+3]; t4 += red[wv*6+4]; t5 += red[wv*6+5];
        }
        p.out[2 + b]  = (t1 > 0.f) ? t0 / fmaxf(t1, 1.f) : 0.f;
        float ph      = (t3 > 0.f) ? t2 / fmaxf(t3, 1.f) : 0.f;
        float po      = (t5 > 0.f) ? t4 / fmaxf(t5, 1.f) : 0.f;
        p.out[10 + b] = ph + po;
        float* pp = p.partials + b * 6;
        pp[0]=t0; pp[1]=t1; pp[2]=t2; pp[3]=t3; pp[4]=t4; pp[5]=t5;
    }
}

// ---------------------------------------------------------------------------
__global__ __launch_bounds__(256, 4) void contact_fused(Params p) {
    __shared__ float4 s_tri[MAXCHUNK_F4];
    cg::grid_group grid = cg::this_grid();
    const int tid  = threadIdx.x;
    const int gtid = blockIdx.x * 256 + tid;
    const int nthreads = gridDim.x * 256;

    // ---- phase 0: zero hit counters + triangle precompute ----
    int nHits = p.B * (p.No + p.Nh);
    for (int i = gtid; i < nHits; i += nthreads) p.hits[i] = 0;
    int nH = p.B * p.Fh;
    int nT = nH + p.B * p.Fo;
    for (int i = gtid; i < nT; i += nthreads) {
        if (i < nH) {
            int b = i / p.Fh;
            tri_pre_one(p.hand_verts + (size_t)b * p.Nh * 3,
                        p.hand_faces + (size_t)i * 3, true, p.htri + (size_t)i * 4);
        } else {
            int j = i - nH;
            int b = j / p.Fo, t = j - b * p.Fo;
            tri_pre_one(p.obj_verts + (size_t)b * p.No * 3,
                        p.obj_faces + (size_t)j * 3, t < p.ofsplit[b],
                        p.otri + (size_t)j * 4);
        }
    }
    grid.sync();

    // ---- phase 1: raycast (virtual blocks), then argmin (waves) ----
    int nVB = p.blocksA + p.blocksB;
    for (int vb = blockIdx.x; vb < nVB; vb += gridDim.x)
        raycast_vb(p, vb, tid, s_tri);

    int lane = tid & 63;
    int gw = gtid >> 6;
    int nWaves = nthreads >> 6;
    int totalMin = p.B * (p.Nh + p.No);
    for (int w = gw; w < totalMin; w += nWaves)
        min_one(p, w, lane);
    grid.sync();

    // ---- phase 2: per-batch reduce ----
    if (blockIdx.x < p.B)
        reduce_batch_one(p, blockIdx.x, tid, (float*)s_tri);
    grid.sync();

    // ---- phase 3: finalize global losses ----
    if (gtid == 0) {
        float sm=0.f,cm=0.f,sph=0.f,cph=0.f,spo=0.f,cpo=0.f;
        for (int b = 0; b < p.B; ++b) {
            const float* pp = p.partials + b * 6;
            sm  += pp[0]; cm  += pp[1]; sph += pp[2];
            cph += pp[3]; spo += pp[4]; cpo += pp[5];
        }
        float missed = (cm  > 0.f) ? sm  / fmaxf(cm , 1.f) : 0.f;
        float ph     = (cph > 0.f) ? sph / fmaxf(cph, 1.f) : 0.f;
        float po     = (cpo > 0.f) ? spo / fmaxf(cpo, 1.f) : 0.f;
        p.out[0] = missed;
        p.out[1] = ph + po;
    }
}

// ---------------------------------------------------------------------------
extern "C" void kernel_launch(void* const* d_in, const int* in_sizes, int n_in,
                              void* d_out, int out_size, void* d_ws, size_t ws_size,
                              hipStream_t stream) {
    Params p;
    p.hand_verts = (const float*)d_in[0];
    p.hand_faces = (const int*)d_in[1];
    p.obj_verts  = (const float*)d_in[2];
    p.obj_faces  = (const int*)d_in[3];
    p.ovsplit    = (const int*)d_in[4];
    p.ofsplit    = (const int*)d_in[5];
    p.out        = (float*)d_out;

    p.B  = in_sizes[4];
    p.Nh = in_sizes[0] / (3 * p.B);
    p.Fh = in_sizes[1] / (3 * p.B);
    p.No = in_sizes[2] / (3 * p.B);
    p.Fo = in_sizes[3] / (3 * p.B);

    char* ws = (char*)d_ws;
    size_t off = 0;
    auto alloc = [&](size_t bytes) -> void* {
        void* q = ws + off;
        off = (off + bytes + 255) & ~(size_t)255;
        return q;
    };
    p.htri     = (float4*)alloc((size_t)p.B * p.Fh * 4 * sizeof(float4));
    p.otri     = (float4*)alloc((size_t)p.B * p.Fo * 4 * sizeof(float4));
    p.hits     = (int*)   alloc((size_t)p.B * (p.No + p.Nh) * sizeof(int));
    p.anchor_h = (float*) alloc((size_t)p.B * p.Nh * sizeof(float));
    p.anchor_o = (float*) alloc((size_t)p.B * p.No * sizeof(float));
    p.partials = (float*) alloc((size_t)p.B * 6 * sizeof(float));

    p.CA = 16; p.CB = 32;
    p.chunkA = (p.Fh + p.CA - 1) / p.CA;       // 97  for Fh=1538 (388 f4 <= 512)
    p.chunkB = (p.Fo + p.CB - 1) / p.CB;       // 125 for Fo=4000 (500 f4 <= 512)
    p.pbA = (p.No + 255) / 256;
    p.pbB = (p.Nh + 255) / 256;
    p.blocksA = p.pbA * p.CA * p.B;            // 1024
    p.blocksB = p.pbB * p.CB * p.B;            // 1024

    // Grid: target 1024 blocks (4/CU at __launch_bounds__(256,4)); clamp to
    // what the occupancy API guarantees co-resident for cooperative launch.
    int maxPerCU = 0, nCU = 0;
    hipOccupancyMaxActiveBlocksPerMultiprocessor(&maxPerCU, contact_fused, 256, 0);
    hipDeviceGetAttribute(&nCU, hipDeviceAttributeMultiprocessorCount, 0);
    int grid = maxPerCU * nCU;
    if (grid > 1024) grid = 1024;
    if (grid < 64)   grid = 64;                // paranoia floor

    void* args[] = { (void*)&p };
    hipLaunchCooperativeKernel((const void*)contact_fused, dim3(grid), dim3(256),
                               args, 0, stream);
}

// Round 4
// 301.960 us; speedup vs baseline: 1.7013x; 1.7013x over previous
//
#include <hip/hip_runtime.h>
#include <hip/hip_bf16.h>

// ContactLoss: Möller–Trumbore parity ray-cast (x2) + nearest-neighbor anchors
// + masked tanh means. All fp32, fp-contract OFF to bit-match numpy reference.
//
// R4: two dispatches, no cooperative sync (R3 showed cg grid.sync costs
// ~100+us each on ROCm).
//   K1 prep: zero hits + done counter, triangle precompute (both meshes).
//   K2 mega: [raycast virtual blocks | argmin blocks] concatenated; last
//            finished block (device atomic + threadfence) runs the reduce.

#define RX 0.4395064455f
#define RY 0.617598629942f
#define RZ 0.652231566745f

#define MAXCHUNK_F4 512   // LDS float4 slots; >= max(chunkA,chunkB)*4

struct Params {
    const float* hand_verts; const int* hand_faces;
    const float* obj_verts;  const int* obj_faces;
    const int* ovsplit; const int* ofsplit;
    float4* htri; float4* otri;
    int* hits;                 // [B*No] obj hits, then [B*Nh] hand hits
    float* anchor_h; float* anchor_o;
    unsigned int* done;
    float* out;
    int B, Nh, Fh, No, Fo;
    int pbA, CA, chunkA, blocksA;
    int pbB, CB, chunkB, blocksB;
    int nMinBlocks;
};

// ---------------------------------------------------------------------------
__device__ __forceinline__ void tri_pre_one(const float* __restrict__ vb,
                                            const int* __restrict__ f,
                                            bool split_ok, float4* __restrict__ o) {
#pragma clang fp contract(off)
    int i0 = f[0], i1 = f[1], i2 = f[2];
    float v0x = vb[i0*3+0], v0y = vb[i0*3+1], v0z = vb[i0*3+2];
    float v1x = vb[i1*3+0], v1y = vb[i1*3+1], v1z = vb[i1*3+2];
    float v2x = vb[i2*3+0], v2y = vb[i2*3+1], v2z = vb[i2*3+2];
    float e1x = v1x - v0x, e1y = v1y - v0y, e1z = v1z - v0z;
    float e2x = v2x - v0x, e2y = v2y - v0y, e2z = v2z - v0z;
    float px = RY*e2z - RZ*e2y;
    float py = RZ*e2x - RX*e2z;
    float pz = RX*e2y - RY*e2x;
    float det = (e1x*px + e1y*py) + e1z*pz;       // ((a+b)+c) like np.sum
    float invdet = 1.0f / (det + 1e-8f);          // 0.1*TOL, IEEE div
    bool valid = !(fabsf(det) < 1e-7f) && split_ok;
    o[0] = make_float4(v0x, v0y, v0z, invdet);
    o[1] = make_float4(e1x, e1y, e1z, valid ? 1.0f : 0.0f);
    o[2] = make_float4(e2x, e2y, e2z, 0.0f);
    o[3] = make_float4(px,  py,  pz,  0.0f);
}

// K1: zero counters + triangle precompute (both meshes).
__global__ __launch_bounds__(256) void prep(Params p) {
    int i = blockIdx.x * blockDim.x + threadIdx.x;
    if (i == 0) *p.done = 0u;
    int nHits = p.B * (p.No + p.Nh);
    if (i < nHits) p.hits[i] = 0;
    int nH = p.B * p.Fh;
    int nT = nH + p.B * p.Fo;
    if (i < nT) {
        if (i < nH) {
            int b = i / p.Fh;
            tri_pre_one(p.hand_verts + (size_t)b * p.Nh * 3,
                        p.hand_faces + (size_t)i * 3, true, p.htri + (size_t)i * 4);
        } else {
            int j = i - nH;
            int b = j / p.Fo, t = j - b * p.Fo;
            tri_pre_one(p.obj_verts + (size_t)b * p.No * 3,
                        p.obj_faces + (size_t)j * 3, t < p.ofsplit[b],
                        p.otri + (size_t)j * 4);
        }
    }
}

// ---------------------------------------------------------------------------
// One raycast virtual block (identical arithmetic to the absmax-0.0 kernel).
// ---------------------------------------------------------------------------
__device__ __forceinline__ void raycast_vb(const Params& p, int vb, int tid,
                                           float4* s_tri) {
#pragma clang fp contract(off)
    const float* pts; const float4* tri; int* hits;
    int P, T, c, pb, b, chunk, tlim, plim;
    if (vb < p.blocksA) {
        int per_b = p.pbA * p.CA;
        b  = vb / per_b;
        int r = vb - b * per_b;
        c  = r / p.pbA;
        pb = r - c * p.pbA;
        pts = p.obj_verts; tri = p.htri; hits = p.hits;
        P = p.No; T = p.Fh; chunk = p.chunkA;
        tlim = p.Fh; plim = min(p.No, p.ovsplit[b]);   // invalid pts never read
    } else {
        int j = vb - p.blocksA;
        int per_b = p.pbB * p.CB;
        b  = j / per_b;
        int r = j - b * per_b;
        c  = r / p.pbB;
        pb = r - c * p.pbB;
        pts = p.hand_verts; tri = p.otri; hits = p.hits + (size_t)p.B * p.No;
        P = p.Nh; T = p.Fo; chunk = p.chunkB;
        tlim = min(p.Fo, p.ofsplit[b]); plim = p.Nh;
    }

    int tStart = c * chunk;
    if (tStart >= tlim) return;           // block-uniform
    if (pb * 256 >= plim) return;         // block-uniform
    int nTri = min(tStart + chunk, tlim) - tStart;

    const float4* src = tri + ((size_t)b * T + tStart) * 4;
    int n4 = nTri * 4;
    for (int j = tid; j < n4; j += 256) s_tri[j] = src[j];

    int pp = pb * 256 + tid;
    bool act = pp < plim;
    float qx = 0.f, qy = 0.f, qz = 0.f;
    if (act) {
        const float* q = pts + ((size_t)b * P + pp) * 3;
        qx = q[0]; qy = q[1]; qz = q[2];
    }
    __syncthreads();

    if (act) {
        int cnt = 0;
        for (int i = 0; i < nTri; ++i) {
            const float4 f0 = s_tri[(i<<2)+0];
            const float4 f1 = s_tri[(i<<2)+1];
            const float4 f2 = s_tri[(i<<2)+2];
            const float4 f3 = s_tri[(i<<2)+3];
            float tvx = qx - f0.x, tvy = qy - f0.y, tvz = qz - f0.z;
            float u  = ((tvx*f3.x + tvy*f3.y) + tvz*f3.z) * f0.w;
            float qvx = tvy*f1.z - tvz*f1.y;
            float qvy = tvz*f1.x - tvx*f1.z;
            float qvz = tvx*f1.y - tvy*f1.x;
            float v  = ((qvx*RX + qvy*RY) + qvz*RZ) * f0.w;
            float tt = ((f2.x*qvx + f2.y*qvy) + f2.z*qvz) * f0.w;
            bool hit = (u > 0.0f) && (u < 1.0f) && (v > 0.0f) &&
                       ((u + v) < 1.0f) && (tt > 1e-7f) && (f1.w != 0.0f);
            cnt += hit ? 1 : 0;
        }
        if (cnt) atomicAdd(&hits[(size_t)b * P + pp], cnt);
    }
}

// ---------------------------------------------------------------------------
// One argmin wave. Packed (dist<<32)|idx min => np.argmin tie-break.
// ---------------------------------------------------------------------------
__device__ __forceinline__ void min_one(const Params& p, int w, int lane) {
#pragma clang fp contract(off)
    int nHand = p.B * p.Nh;
    const float* refv; const float* loopv; int loopN; float* outp;
    if (w < nHand) {
        int b = w / p.Nh;
        int n = w - b * p.Nh;
        refv  = p.hand_verts + ((size_t)b * p.Nh + n) * 3;
        loopv = p.obj_verts + (size_t)b * p.No * 3;
        loopN = p.ovsplit[b];
        outp  = p.anchor_h + (size_t)b * p.Nh + n;
    } else {
        int j = w - nHand;
        int b = j / p.No;
        int m = j - b * p.No;
        if (m >= p.ovsplit[b]) return;
        refv  = p.obj_verts + ((size_t)b * p.No + m) * 3;
        loopv = p.hand_verts + (size_t)b * p.Nh * 3;
        loopN = p.Nh;
        outp  = p.anchor_o + (size_t)b * p.No + m;
    }
    float hx = refv[0], hy = refv[1], hz = refv[2];
    float rx = (hx*hx + hy*hy) + hz*hz;
    unsigned long long best = ~0ull;
    for (int m = lane; m < loopN; m += 64) {
        float ox = loopv[m*3+0], oy = loopv[m*3+1], oz = loopv[m*3+2];
        float ry = (ox*ox + oy*oy) + oz*oz;
        float zz = (hx*ox + hy*oy) + hz*oz;
        float d = (rx + ry) - 2.0f * zz;
        unsigned long long e = ((unsigned long long)__float_as_uint(d) << 32) | (unsigned)m;
        if (e < best) best = e;
    }
    for (int off = 32; off > 0; off >>= 1) {
        unsigned long long o = __shfl_xor(best, off, 64);
        if (o < best) best = o;
    }
    if (lane == 0) {
        int idx = (best == ~0ull) ? 0 : (int)(best & 0xffffffffu);
        const float* cv = loopv + (size_t)idx * 3;
        float dx = cv[0] - hx, dy = cv[1] - hy, dz = cv[2] - hz;
        *outp = sqrtf((dx*dx + dy*dy) + dz*dz);
    }
}

// ---------------------------------------------------------------------------
// Per-batch masked sums for batch b, 256 threads. Barrier at entry protects
// the shared buffer from the previous batch's readers.
// ---------------------------------------------------------------------------
__device__ __forceinline__ void reduce_batch_one(const Params& p, int b, int tid,
                                                 float* red, float* partials) {
    __syncthreads();
    int wave = tid >> 6, lane = tid & 63;
    const int* hits_obj  = p.hits;
    const int* hits_hand = p.hits + (size_t)p.B * p.No;
    float s0=0.f,s1=0.f,s2=0.f,s3=0.f,s4=0.f,s5=0.f;
    for (int n = tid; n < p.Nh; n += 256) {
        bool ext = (hits_hand[(size_t)b*p.Nh + n] & 1) == 0;
        float val = 25.0f * tanhf(p.anchor_h[(size_t)b*p.Nh + n] / 25.0f);
        if (ext) { s0 += val; s1 += 1.0f; } else { s2 += val; s3 += 1.0f; }
    }
    int split = p.ovsplit[b];
    for (int m = tid; m < split; m += 256) {
        if ((hits_obj[(size_t)b*p.No + m] & 1) != 0) {   // interior & valid
            s4 += 25.0f * tanhf(p.anchor_o[(size_t)b*p.No + m] / 25.0f);
            s5 += 1.0f;
        }
    }
    for (int off = 32; off > 0; off >>= 1) {
        s0 += __shfl_xor(s0, off, 64);
        s1 += __shfl_xor(s1, off, 64);
        s2 += __shfl_xor(s2, off, 64);
        s3 += __shfl_xor(s3, off, 64);
        s4 += __shfl_xor(s4, off, 64);
        s5 += __shfl_xor(s5, off, 64);
    }
    if (lane == 0) {
        red[wave*6+0]=s0; red[wave*6+1]=s1; red[wave*6+2]=s2;
        red[wave*6+3]=s3; red[wave*6+4]=s4; red[wave*6+5]=s5;
    }
    __syncthreads();
    if (tid == 0) {
        float t0=0.f,t1=0.f,t2=0.f,t3=0.f,t4=0.f,t5=0.f;
        for (int wv = 0; wv < 4; ++wv) {
            t0 += red[wv*6+0]; t1 += red[wv*6+1]; t2 += red[wv*6+2];
            t3 += red[wv*6+3]; t4 += red[wv*6+4]; t5 += red[wv*6+5];
        }
        p.out[2 + b]  = (t1 > 0.f) ? t0 / fmaxf(t1, 1.f) : 0.f;
        float ph      = (t3 > 0.f) ? t2 / fmaxf(t3, 1.f) : 0.f;
        float po      = (t5 > 0.f) ? t4 / fmaxf(t5, 1.f) : 0.f;
        p.out[10 + b] = ph + po;
        partials[b*6+0]=t0; partials[b*6+1]=t1; partials[b*6+2]=t2;
        partials[b*6+3]=t3; partials[b*6+4]=t4; partials[b*6+5]=t5;
    }
}

// ---------------------------------------------------------------------------
// K2: [raycast VBs | argmin blocks]; last finished block runs the reduce.
// ---------------------------------------------------------------------------
__global__ __launch_bounds__(256) void mega(Params p) {
    __shared__ float4 s_tri[MAXCHUNK_F4];
    __shared__ bool s_last;
    __shared__ float s_partials[8 * 6];
    const int tid = threadIdx.x;
    const int bid = blockIdx.x;
    const int nRay = p.blocksA + p.blocksB;

    if (bid < nRay) {
        raycast_vb(p, bid, tid, s_tri);
    } else {
        int j = bid - nRay;
        int w = j * 4 + (tid >> 6);
        if (w < p.B * (p.Nh + p.No)) min_one(p, w, tid & 63);
    }

    // ---- last-block-done tail ----
    __syncthreads();                       // all block work complete
    if (tid == 0) {
        __threadfence();                   // release our stores/atomics
        unsigned int old = atomicAdd(p.done, 1u);
        s_last = (old == (unsigned int)(gridDim.x - 1));
    }
    __syncthreads();
    if (!s_last) return;

    __threadfence();                       // acquire others' stores
    float* red = (float*)s_tri;
    for (int b = 0; b < p.B; ++b)
        reduce_batch_one(p, b, tid, red, s_partials);
    __syncthreads();
    if (tid == 0) {
        float sm=0.f,cm=0.f,sph=0.f,cph=0.f,spo=0.f,cpo=0.f;
        for (int b = 0; b < p.B; ++b) {
            sm  += s_partials[b*6+0]; cm  += s_partials[b*6+1];
            sph += s_partials[b*6+2]; cph += s_partials[b*6+3];
            spo += s_partials[b*6+4]; cpo += s_partials[b*6+5];
        }
        float missed = (cm  > 0.f) ? sm  / fmaxf(cm , 1.f) : 0.f;
        float ph     = (cph > 0.f) ? sph / fmaxf(cph, 1.f) : 0.f;
        float po     = (cpo > 0.f) ? spo / fmaxf(cpo, 1.f) : 0.f;
        p.out[0] = missed;
        p.out[1] = ph + po;
    }
}

// ---------------------------------------------------------------------------
extern "C" void kernel_launch(void* const* d_in, const int* in_sizes, int n_in,
                              void* d_out, int out_size, void* d_ws, size_t ws_size,
                              hipStream_t stream) {
    Params p;
    p.hand_verts = (const float*)d_in[0];
    p.hand_faces = (const int*)d_in[1];
    p.obj_verts  = (const float*)d_in[2];
    p.obj_faces  = (const int*)d_in[3];
    p.ovsplit    = (const int*)d_in[4];
    p.ofsplit    = (const int*)d_in[5];
    p.out        = (float*)d_out;

    p.B  = in_sizes[4];
    p.Nh = in_sizes[0] / (3 * p.B);
    p.Fh = in_sizes[1] / (3 * p.B);
    p.No = in_sizes[2] / (3 * p.B);
    p.Fo = in_sizes[3] / (3 * p.B);

    char* ws = (char*)d_ws;
    size_t off = 0;
    auto alloc = [&](size_t bytes) -> void* {
        void* q = ws + off;
        off = (off + bytes + 255) & ~(size_t)255;
        return q;
    };
    p.htri     = (float4*)alloc((size_t)p.B * p.Fh * 4 * sizeof(float4));
    p.otri     = (float4*)alloc((size_t)p.B * p.Fo * 4 * sizeof(float4));
    p.hits     = (int*)   alloc((size_t)p.B * (p.No + p.Nh) * sizeof(int));
    p.anchor_h = (float*) alloc((size_t)p.B * p.Nh * sizeof(float));
    p.anchor_o = (float*) alloc((size_t)p.B * p.No * sizeof(float));
    p.done     = (unsigned int*)alloc(sizeof(unsigned int));

    p.CA = 16; p.CB = 32;
    p.chunkA = (p.Fh + p.CA - 1) / p.CA;       // 97  for Fh=1538 (388 f4 <= 512)
    p.chunkB = (p.Fo + p.CB - 1) / p.CB;       // 125 for Fo=4000 (500 f4 <= 512)
    p.pbA = (p.No + 255) / 256;
    p.pbB = (p.Nh + 255) / 256;
    p.blocksA = p.pbA * p.CA * p.B;            // 1024
    p.blocksB = p.pbB * p.CB * p.B;            // 1024
    int totalMin = p.B * (p.Nh + p.No);
    p.nMinBlocks = (totalMin + 3) / 4;         // 4 waves per block

    // K1: prep (zero hits/done + tri_pre).
    int nT = p.B * (p.Fh + p.Fo);
    int nHits = p.B * (p.No + p.Nh);
    int prepThreads = nT > nHits ? nT : nHits;
    prep<<<(prepThreads + 255) / 256, 256, 0, stream>>>(p);

    // K2: mega (raycast + argmin + last-block reduce).
    int grid = p.blocksA + p.blocksB + p.nMinBlocks;
    mega<<<grid, 256, 0, stream>>>(p);
}

// Round 5
// 147.880 us; speedup vs baseline: 3.4740x; 2.0419x over previous
//
#include <hip/hip_runtime.h>
#include <hip/hip_bf16.h>

// ContactLoss: Möller–Trumbore parity ray-cast (x2) + nearest-neighbor anchors
// + masked tanh means. All fp32, fp-contract OFF to bit-match numpy reference.
//
// R5: 3 dispatches, NO global sync primitives.
//  - mega:   [raycast virtual blocks | argmin blocks]. Each raycast block
//            computes its triangle chunk inline into LDS (no tri_pre kernel,
//            no global tri arrays) and writes hit counts to private
//            per-(chunk,batch,point) slots with plain stores (no atomics,
//            no zero-init needed).
//  - reduce8: one block per batch sums chunk slots (parity) + tanh means.
//  - fin:     global losses from per-batch partials.
// R4 lesson: grid-wide done-counter (7.6K same-line device atomics + agent
// fences) cost ~170us. Kernel-boundary ordering is free.

#define RX 0.4395064455f
#define RY 0.617598629942f
#define RZ 0.652231566745f

#define MAXCHUNK_F4 512   // LDS float4 slots; >= max(chunkA,chunkB)*4

struct Params {
    const float* hand_verts; const int* hand_faces;
    const float* obj_verts;  const int* obj_faces;
    const int* ovsplit; const int* ofsplit;
    int* hitsA;                // [CA*B*No] pass-A per-chunk hit counts
    int* hitsB;                // [CB*B*Nh] pass-B per-chunk hit counts
    float* anchor_h; float* anchor_o; float* partials;
    float* out;
    int B, Nh, Fh, No, Fo;
    int pbA, CA, chunkA, blocksA;
    int pbB, CB, chunkB, blocksB;
};

// ---------------------------------------------------------------------------
// Per-triangle precompute (identical arithmetic to the absmax-0.0 lineage).
// Writes {v0.xyz,invdet},{e1.xyz,flag},{e2.xyz,0},{pvec.xyz,0} to o[0..3].
// ---------------------------------------------------------------------------
__device__ __forceinline__ void tri_pre_one(const float* __restrict__ vb,
                                            const int* __restrict__ f,
                                            float4* o) {
#pragma clang fp contract(off)
    int i0 = f[0], i1 = f[1], i2 = f[2];
    float v0x = vb[i0*3+0], v0y = vb[i0*3+1], v0z = vb[i0*3+2];
    float v1x = vb[i1*3+0], v1y = vb[i1*3+1], v1z = vb[i1*3+2];
    float v2x = vb[i2*3+0], v2y = vb[i2*3+1], v2z = vb[i2*3+2];
    float e1x = v1x - v0x, e1y = v1y - v0y, e1z = v1z - v0z;
    float e2x = v2x - v0x, e2y = v2y - v0y, e2z = v2z - v0z;
    float px = RY*e2z - RZ*e2y;
    float py = RZ*e2x - RX*e2z;
    float pz = RX*e2y - RY*e2x;
    float det = (e1x*px + e1y*py) + e1z*pz;       // ((a+b)+c) like np.sum
    float invdet = 1.0f / (det + 1e-8f);          // 0.1*TOL, IEEE div
    bool valid = !(fabsf(det) < 1e-7f);
    o[0] = make_float4(v0x, v0y, v0z, invdet);
    o[1] = make_float4(e1x, e1y, e1z, valid ? 1.0f : 0.0f);
    o[2] = make_float4(e2x, e2y, e2z, 0.0f);
    o[3] = make_float4(px,  py,  pz,  0.0f);
}

// ---------------------------------------------------------------------------
// One raycast virtual block. Triangle chunk computed INLINE into LDS by
// threads 0..nTri-1; every in-range point stores its count to a private slot.
// ---------------------------------------------------------------------------
__device__ __forceinline__ void raycast_vb(const Params& p, int vbid, int tid,
                                           float4* s_tri) {
#pragma clang fp contract(off)
    const float* pts; const float* tverts; const int* tfaces; int* slots;
    int P, T, Nv, c, pb, b, chunk, tlim, plim;
    if (vbid < p.blocksA) {
        int per_b = p.pbA * p.CA;
        b  = vbid / per_b;
        int r = vbid - b * per_b;
        c  = r / p.pbA;
        pb = r - c * p.pbA;
        pts = p.obj_verts; tverts = p.hand_verts; tfaces = p.hand_faces;
        slots = p.hitsA;
        P = p.No; T = p.Fh; Nv = p.Nh; chunk = p.chunkA;
        tlim = p.Fh; plim = min(p.No, p.ovsplit[b]);   // invalid pts never read
    } else {
        int j = vbid - p.blocksA;
        int per_b = p.pbB * p.CB;
        b  = j / per_b;
        int r = j - b * per_b;
        c  = r / p.pbB;
        pb = r - c * p.pbB;
        pts = p.hand_verts; tverts = p.obj_verts; tfaces = p.obj_faces;
        slots = p.hitsB;
        P = p.Nh; T = p.Fo; Nv = p.No; chunk = p.chunkB;
        tlim = min(p.Fo, p.ofsplit[b]); plim = p.Nh;
    }

    int tStart = c * chunk;
    if (tStart >= tlim) return;           // block-uniform (slots unread)
    if (pb * 256 >= plim) return;         // block-uniform (slots unread)
    int nTri = min(tStart + chunk, tlim) - tStart;

    if (tid < nTri) {
        int t = tStart + tid;
        tri_pre_one(tverts + (size_t)b * Nv * 3,
                    tfaces + ((size_t)b * T + t) * 3,
                    s_tri + (size_t)tid * 4);
    }

    int pp = pb * 256 + tid;
    bool act = pp < plim;
    float qx = 0.f, qy = 0.f, qz = 0.f;
    if (act) {
        const float* q = pts + ((size_t)b * P + pp) * 3;
        qx = q[0]; qy = q[1]; qz = q[2];
    }
    __syncthreads();

    if (act) {
        int cnt = 0;
        for (int i = 0; i < nTri; ++i) {
            const float4 f0 = s_tri[(i<<2)+0];
            const float4 f1 = s_tri[(i<<2)+1];
            const float4 f2 = s_tri[(i<<2)+2];
            const float4 f3 = s_tri[(i<<2)+3];
            float tvx = qx - f0.x, tvy = qy - f0.y, tvz = qz - f0.z;
            float u  = ((tvx*f3.x + tvy*f3.y) + tvz*f3.z) * f0.w;
            float qvx = tvy*f1.z - tvz*f1.y;
            float qvy = tvz*f1.x - tvx*f1.z;
            float qvz = tvx*f1.y - tvy*f1.x;
            float v  = ((qvx*RX + qvy*RY) + qvz*RZ) * f0.w;
            float tt = ((f2.x*qvx + f2.y*qvy) + f2.z*qvz) * f0.w;
            bool hit = (u > 0.0f) && (u < 1.0f) && (v > 0.0f) &&
                       ((u + v) < 1.0f) && (tt > 1e-7f) && (f1.w != 0.0f);
            cnt += hit ? 1 : 0;
        }
        slots[((size_t)(c * p.B + b)) * P + pp] = cnt;   // plain store
    }
}

// ---------------------------------------------------------------------------
// One argmin wave. Packed (dist<<32)|idx min => np.argmin tie-break.
// ---------------------------------------------------------------------------
__device__ __forceinline__ void min_one(const Params& p, int w, int lane) {
#pragma clang fp contract(off)
    int nHand = p.B * p.Nh;
    const float* refv; const float* loopv; int loopN; float* outp;
    if (w < nHand) {
        int b = w / p.Nh;
        int n = w - b * p.Nh;
        refv  = p.hand_verts + ((size_t)b * p.Nh + n) * 3;
        loopv = p.obj_verts + (size_t)b * p.No * 3;
        loopN = p.ovsplit[b];
        outp  = p.anchor_h + (size_t)b * p.Nh + n;
    } else {
        int j = w - nHand;
        int b = j / p.No;
        int m = j - b * p.No;
        if (m >= p.ovsplit[b]) return;
        refv  = p.obj_verts + ((size_t)b * p.No + m) * 3;
        loopv = p.hand_verts + (size_t)b * p.Nh * 3;
        loopN = p.Nh;
        outp  = p.anchor_o + (size_t)b * p.No + m;
    }
    float hx = refv[0], hy = refv[1], hz = refv[2];
    float rx = (hx*hx + hy*hy) + hz*hz;
    unsigned long long best = ~0ull;
    for (int m = lane; m < loopN; m += 64) {
        float ox = loopv[m*3+0], oy = loopv[m*3+1], oz = loopv[m*3+2];
        float ry = (ox*ox + oy*oy) + oz*oz;
        float zz = (hx*ox + hy*oy) + hz*oz;
        float d = (rx + ry) - 2.0f * zz;
        unsigned long long e = ((unsigned long long)__float_as_uint(d) << 32) | (unsigned)m;
        if (e < best) best = e;
    }
    for (int off = 32; off > 0; off >>= 1) {
        unsigned long long o = __shfl_xor(best, off, 64);
        if (o < best) best = o;
    }
    if (lane == 0) {
        int idx = (best == ~0ull) ? 0 : (int)(best & 0xffffffffu);
        const float* cv = loopv + (size_t)idx * 3;
        float dx = cv[0] - hx, dy = cv[1] - hy, dz = cv[2] - hz;
        *outp = sqrtf((dx*dx + dy*dy) + dz*dz);
    }
}

// ---------------------------------------------------------------------------
// mega: [raycast VBs | argmin blocks] — no tail, no atomics, no fences.
// ---------------------------------------------------------------------------
__global__ __launch_bounds__(256) void mega(Params p) {
    __shared__ float4 s_tri[MAXCHUNK_F4];
    const int tid = threadIdx.x;
    const int bid = blockIdx.x;
    const int nRay = p.blocksA + p.blocksB;
    if (bid < nRay) {
        raycast_vb(p, bid, tid, s_tri);
    } else {
        int w = (bid - nRay) * 4 + (tid >> 6);
        if (w < p.B * (p.Nh + p.No)) min_one(p, w, tid & 63);
    }
}

// ---------------------------------------------------------------------------
// reduce8: block b = batch b. Sums per-chunk slots (parity) + tanh means.
// ---------------------------------------------------------------------------
__global__ __launch_bounds__(1024) void reduce8(Params p) {
    const int b = blockIdx.x, tid = threadIdx.x;
    const int wave = tid >> 6, lane = tid & 63;
    float s0=0.f,s1=0.f,s2=0.f,s3=0.f,s4=0.f,s5=0.f;

    int tlimB = min(p.Fo, p.ofsplit[b]);
    int nCB = (tlimB + p.chunkB - 1) / p.chunkB;        // valid pass-B chunks
    for (int n = tid; n < p.Nh; n += 1024) {
        int par = 0;
        for (int c = 0; c < nCB; ++c)
            par += p.hitsB[((size_t)(c * p.B + b)) * p.Nh + n];
        bool ext = (par & 1) == 0;
        float val = 25.0f * tanhf(p.anchor_h[(size_t)b*p.Nh + n] / 25.0f);
        if (ext) { s0 += val; s1 += 1.0f; } else { s2 += val; s3 += 1.0f; }
    }
    int split = p.ovsplit[b];
    for (int m = tid; m < split; m += 1024) {
        int par = 0;
        for (int c = 0; c < p.CA; ++c)
            par += p.hitsA[((size_t)(c * p.B + b)) * p.No + m];
        if (par & 1) {                                   // interior & valid
            s4 += 25.0f * tanhf(p.anchor_o[(size_t)b*p.No + m] / 25.0f);
            s5 += 1.0f;
        }
    }
    for (int off = 32; off > 0; off >>= 1) {
        s0 += __shfl_xor(s0, off, 64);
        s1 += __shfl_xor(s1, off, 64);
        s2 += __shfl_xor(s2, off, 64);
        s3 += __shfl_xor(s3, off, 64);
        s4 += __shfl_xor(s4, off, 64);
        s5 += __shfl_xor(s5, off, 64);
    }
    __shared__ float red[16][6];
    if (lane == 0) {
        red[wave][0]=s0; red[wave][1]=s1; red[wave][2]=s2;
        red[wave][3]=s3; red[wave][4]=s4; red[wave][5]=s5;
    }
    __syncthreads();
    if (tid == 0) {
        float t0=0.f,t1=0.f,t2=0.f,t3=0.f,t4=0.f,t5=0.f;
        for (int wv = 0; wv < 16; ++wv) {
            t0 += red[wv][0]; t1 += red[wv][1]; t2 += red[wv][2];
            t3 += red[wv][3]; t4 += red[wv][4]; t5 += red[wv][5];
        }
        p.out[2 + b]  = (t1 > 0.f) ? t0 / fmaxf(t1, 1.f) : 0.f;
        float ph      = (t3 > 0.f) ? t2 / fmaxf(t3, 1.f) : 0.f;
        float po      = (t5 > 0.f) ? t4 / fmaxf(t5, 1.f) : 0.f;
        p.out[10 + b] = ph + po;
        float* pp = p.partials + b * 6;
        pp[0]=t0; pp[1]=t1; pp[2]=t2; pp[3]=t3; pp[4]=t4; pp[5]=t5;
    }
}

// ---------------------------------------------------------------------------
__global__ void fin(Params p) {
    if (threadIdx.x == 0 && blockIdx.x == 0) {
        float sm=0.f,cm=0.f,sph=0.f,cph=0.f,spo=0.f,cpo=0.f;
        for (int b = 0; b < p.B; ++b) {
            const float* pp = p.partials + b * 6;
            sm  += pp[0]; cm  += pp[1]; sph += pp[2];
            cph += pp[3]; spo += pp[4]; cpo += pp[5];
        }
        float missed = (cm  > 0.f) ? sm  / fmaxf(cm , 1.f) : 0.f;
        float ph     = (cph > 0.f) ? sph / fmaxf(cph, 1.f) : 0.f;
        float po     = (cpo > 0.f) ? spo / fmaxf(cpo, 1.f) : 0.f;
        p.out[0] = missed;
        p.out[1] = ph + po;
    }
}

// ---------------------------------------------------------------------------
extern "C" void kernel_launch(void* const* d_in, const int* in_sizes, int n_in,
                              void* d_out, int out_size, void* d_ws, size_t ws_size,
                              hipStream_t stream) {
    Params p;
    p.hand_verts = (const float*)d_in[0];
    p.hand_faces = (const int*)d_in[1];
    p.obj_verts  = (const float*)d_in[2];
    p.obj_faces  = (const int*)d_in[3];
    p.ovsplit    = (const int*)d_in[4];
    p.ofsplit    = (const int*)d_in[5];
    p.out        = (float*)d_out;

    p.B  = in_sizes[4];
    p.Nh = in_sizes[0] / (3 * p.B);
    p.Fh = in_sizes[1] / (3 * p.B);
    p.No = in_sizes[2] / (3 * p.B);
    p.Fo = in_sizes[3] / (3 * p.B);

    p.CA = 16; p.CB = 32;
    p.chunkA = (p.Fh + p.CA - 1) / p.CA;       // 97  for Fh=1538 (388 f4 <= 512)
    p.chunkB = (p.Fo + p.CB - 1) / p.CB;       // 125 for Fo=4000 (500 f4 <= 512)
    p.pbA = (p.No + 255) / 256;
    p.pbB = (p.Nh + 255) / 256;
    p.blocksA = p.pbA * p.CA * p.B;            // 1024
    p.blocksB = p.pbB * p.CB * p.B;            // 1024

    char* ws = (char*)d_ws;
    size_t off = 0;
    auto alloc = [&](size_t bytes) -> void* {
        void* q = ws + off;
        off = (off + bytes + 255) & ~(size_t)255;
        return q;
    };
    p.hitsA    = (int*)   alloc((size_t)p.CA * p.B * p.No * sizeof(int));
    p.hitsB    = (int*)   alloc((size_t)p.CB * p.B * p.Nh * sizeof(int));
    p.anchor_h = (float*) alloc((size_t)p.B * p.Nh * sizeof(float));
    p.anchor_o = (float*) alloc((size_t)p.B * p.No * sizeof(float));
    p.partials = (float*) alloc((size_t)p.B * 6 * sizeof(float));

    int totalMin  = p.B * (p.Nh + p.No);
    int nMinBlocks = (totalMin + 3) / 4;       // 4 argmin waves per block
    int grid = p.blocksA + p.blocksB + nMinBlocks;

    mega<<<grid, 256, 0, stream>>>(p);
    reduce8<<<p.B, 1024, 0, stream>>>(p);
    fin<<<1, 64, 0, stream>>>(p);
}

// Round 6
// 133.688 us; speedup vs baseline: 3.8428x; 1.1062x over previous
//
#include <hip/hip_runtime.h>
#include <hip/hip_bf16.h>

// ContactLoss: Möller–Trumbore parity ray-cast (x2) + nearest-neighbor anchors
// + masked tanh means. All fp32, fp-contract OFF to bit-match numpy reference.
//
// R6: 2 dispatches (~20us/graph-node measured R2/R4/R5).
//  - mega:       [raycast VBs (2 points/thread, tri chunk inline into LDS,
//                 private hit slots, no atomics) | argmin blocks]. Resets done.
//  - reduce_fin: 8 blocks (one per batch); last block (8-way done counter +
//                fences — R4-proven pattern, cheap at 8 blocks) finalizes.

#define RX 0.4395064455f
#define RY 0.617598629942f
#define RZ 0.652231566745f

#define MAXCHUNK_F4 512   // LDS float4 slots; >= max(chunkA,chunkB)*4
#define PTS_PER_BLK 512   // 2 points per thread

struct Params {
    const float* hand_verts; const int* hand_faces;
    const float* obj_verts;  const int* obj_faces;
    const int* ovsplit; const int* ofsplit;
    int* hitsA;                // [CA*B*No] pass-A per-chunk hit counts
    int* hitsB;                // [CB*B*Nh] pass-B per-chunk hit counts
    float* anchor_h; float* anchor_o; float* partials;
    unsigned int* done;
    float* out;
    int B, Nh, Fh, No, Fo;
    int pbA, CA, chunkA, blocksA;
    int pbB, CB, chunkB, blocksB;
};

// ---------------------------------------------------------------------------
// Per-triangle precompute (identical arithmetic to the absmax-0.0 lineage).
// ---------------------------------------------------------------------------
__device__ __forceinline__ void tri_pre_one(const float* __restrict__ vb,
                                            const int* __restrict__ f,
                                            float4* o) {
#pragma clang fp contract(off)
    int i0 = f[0], i1 = f[1], i2 = f[2];
    float v0x = vb[i0*3+0], v0y = vb[i0*3+1], v0z = vb[i0*3+2];
    float v1x = vb[i1*3+0], v1y = vb[i1*3+1], v1z = vb[i1*3+2];
    float v2x = vb[i2*3+0], v2y = vb[i2*3+1], v2z = vb[i2*3+2];
    float e1x = v1x - v0x, e1y = v1y - v0y, e1z = v1z - v0z;
    float e2x = v2x - v0x, e2y = v2y - v0y, e2z = v2z - v0z;
    float px = RY*e2z - RZ*e2y;
    float py = RZ*e2x - RX*e2z;
    float pz = RX*e2y - RY*e2x;
    float det = (e1x*px + e1y*py) + e1z*pz;       // ((a+b)+c) like np.sum
    float invdet = 1.0f / (det + 1e-8f);          // 0.1*TOL, IEEE div
    bool valid = !(fabsf(det) < 1e-7f);
    o[0] = make_float4(v0x, v0y, v0z, invdet);
    o[1] = make_float4(e1x, e1y, e1z, valid ? 1.0f : 0.0f);
    o[2] = make_float4(e2x, e2y, e2z, 0.0f);
    o[3] = make_float4(px,  py,  pz,  0.0f);
}

// One Möller–Trumbore test (expression tree identical to absmax-0.0 lineage).
__device__ __forceinline__ int mt_test(float qx, float qy, float qz,
                                       const float4& f0, const float4& f1,
                                       const float4& f2, const float4& f3) {
#pragma clang fp contract(off)
    float tvx = qx - f0.x, tvy = qy - f0.y, tvz = qz - f0.z;
    float u  = ((tvx*f3.x + tvy*f3.y) + tvz*f3.z) * f0.w;
    float qvx = tvy*f1.z - tvz*f1.y;
    float qvy = tvz*f1.x - tvx*f1.z;
    float qvz = tvx*f1.y - tvy*f1.x;
    float v  = ((qvx*RX + qvy*RY) + qvz*RZ) * f0.w;
    float tt = ((f2.x*qvx + f2.y*qvy) + f2.z*qvz) * f0.w;
    bool hit = (u > 0.0f) && (u < 1.0f) && (v > 0.0f) &&
               ((u + v) < 1.0f) && (tt > 1e-7f) && (f1.w != 0.0f);
    return hit ? 1 : 0;
}

// ---------------------------------------------------------------------------
// One raycast virtual block: triangle chunk built inline into LDS, each
// thread tests TWO points (halves LDS read traffic per test).
// ---------------------------------------------------------------------------
__device__ __forceinline__ void raycast_vb(const Params& p, int vbid, int tid,
                                           float4* s_tri) {
#pragma clang fp contract(off)
    const float* pts; const float* tverts; const int* tfaces; int* slots;
    int P, T, Nv, c, pb, b, chunk, tlim, plim;
    if (vbid < p.blocksA) {
        int per_b = p.pbA * p.CA;
        b  = vbid / per_b;
        int r = vbid - b * per_b;
        c  = r / p.pbA;
        pb = r - c * p.pbA;
        pts = p.obj_verts; tverts = p.hand_verts; tfaces = p.hand_faces;
        slots = p.hitsA;
        P = p.No; T = p.Fh; Nv = p.Nh; chunk = p.chunkA;
        tlim = p.Fh; plim = min(p.No, p.ovsplit[b]);   // invalid pts never read
    } else {
        int j = vbid - p.blocksA;
        int per_b = p.pbB * p.CB;
        b  = j / per_b;
        int r = j - b * per_b;
        c  = r / p.pbB;
        pb = r - c * p.pbB;
        pts = p.hand_verts; tverts = p.obj_verts; tfaces = p.obj_faces;
        slots = p.hitsB;
        P = p.Nh; T = p.Fo; Nv = p.No; chunk = p.chunkB;
        tlim = min(p.Fo, p.ofsplit[b]); plim = p.Nh;
    }

    int tStart = c * chunk;
    if (tStart >= tlim) return;               // block-uniform (slots unread)
    if (pb * PTS_PER_BLK >= plim) return;     // block-uniform (slots unread)
    int nTri = min(tStart + chunk, tlim) - tStart;

    if (tid < nTri) {
        int t = tStart + tid;
        tri_pre_one(tverts + (size_t)b * Nv * 3,
                    tfaces + ((size_t)b * T + t) * 3,
                    s_tri + (size_t)tid * 4);
    }

    int p1 = pb * PTS_PER_BLK + tid;
    int p2 = p1 + 256;
    bool act1 = p1 < plim, act2 = p2 < plim;
    float q1x = 0.f, q1y = 0.f, q1z = 0.f;
    float q2x = 0.f, q2y = 0.f, q2z = 0.f;
    if (act1) {
        const float* q = pts + ((size_t)b * P + p1) * 3;
        q1x = q[0]; q1y = q[1]; q1z = q[2];
    }
    if (act2) {
        const float* q = pts + ((size_t)b * P + p2) * 3;
        q2x = q[0]; q2y = q[1]; q2z = q[2];
    }
    __syncthreads();

    if (!act1) return;                        // act1 false => act2 false
    int cnt1 = 0, cnt2 = 0;
    for (int i = 0; i < nTri; ++i) {
        const float4 f0 = s_tri[(i<<2)+0];
        const float4 f1 = s_tri[(i<<2)+1];
        const float4 f2 = s_tri[(i<<2)+2];
        const float4 f3 = s_tri[(i<<2)+3];
        cnt1 += mt_test(q1x, q1y, q1z, f0, f1, f2, f3);
        cnt2 += mt_test(q2x, q2y, q2z, f0, f1, f2, f3);
    }
    int* base = slots + ((size_t)(c * p.B + b)) * P;
    base[p1] = cnt1;                          // plain stores, no atomics
    if (act2) base[p2] = cnt2;
}

// ---------------------------------------------------------------------------
// One argmin wave. Packed (dist<<32)|idx min => np.argmin tie-break.
// ---------------------------------------------------------------------------
__device__ __forceinline__ void min_one(const Params& p, int w, int lane) {
#pragma clang fp contract(off)
    int nHand = p.B * p.Nh;
    const float* refv; const float* loopv; int loopN; float* outp;
    if (w < nHand) {
        int b = w / p.Nh;
        int n = w - b * p.Nh;
        refv  = p.hand_verts + ((size_t)b * p.Nh + n) * 3;
        loopv = p.obj_verts + (size_t)b * p.No * 3;
        loopN = p.ovsplit[b];
        outp  = p.anchor_h + (size_t)b * p.Nh + n;
    } else {
        int j = w - nHand;
        int b = j / p.No;
        int m = j - b * p.No;
        if (m >= p.ovsplit[b]) return;
        refv  = p.obj_verts + ((size_t)b * p.No + m) * 3;
        loopv = p.hand_verts + (size_t)b * p.Nh * 3;
        loopN = p.Nh;
        outp  = p.anchor_o + (size_t)b * p.No + m;
    }
    float hx = refv[0], hy = refv[1], hz = refv[2];
    float rx = (hx*hx + hy*hy) + hz*hz;
    unsigned long long best = ~0ull;
    for (int m = lane; m < loopN; m += 64) {
        float ox = loopv[m*3+0], oy = loopv[m*3+1], oz = loopv[m*3+2];
        float ry = (ox*ox + oy*oy) + oz*oz;
        float zz = (hx*ox + hy*oy) + hz*oz;
        float d = (rx + ry) - 2.0f * zz;
        unsigned long long e = ((unsigned long long)__float_as_uint(d) << 32) | (unsigned)m;
        if (e < best) best = e;
    }
    for (int off = 32; off > 0; off >>= 1) {
        unsigned long long o = __shfl_xor(best, off, 64);
        if (o < best) best = o;
    }
    if (lane == 0) {
        int idx = (best == ~0ull) ? 0 : (int)(best & 0xffffffffu);
        const float* cv = loopv + (size_t)idx * 3;
        float dx = cv[0] - hx, dy = cv[1] - hy, dz = cv[2] - hz;
        *outp = sqrtf((dx*dx + dy*dy) + dz*dz);
    }
}

// ---------------------------------------------------------------------------
// mega: [raycast VBs | argmin blocks] — no tail sync; resets done counter.
// ---------------------------------------------------------------------------
__global__ __launch_bounds__(256) void mega(Params p) {
    __shared__ float4 s_tri[MAXCHUNK_F4];
    const int tid = threadIdx.x;
    const int bid = blockIdx.x;
    if (bid == 0 && tid == 0) *p.done = 0u;   // visible to reduce_fin at boundary
    const int nRay = p.blocksA + p.blocksB;
    if (bid < nRay) {
        raycast_vb(p, bid, tid, s_tri);
    } else {
        int w = (bid - nRay) * 4 + (tid >> 6);
        if (w < p.B * (p.Nh + p.No)) min_one(p, w, tid & 63);
    }
}

// ---------------------------------------------------------------------------
// reduce_fin: block b = batch b. Sums per-chunk slots (parity) + tanh means;
// last-done block (8-way counter, R4-proven fence pattern) finalizes.
// ---------------------------------------------------------------------------
__global__ __launch_bounds__(1024) void reduce_fin(Params p) {
    const int b = blockIdx.x, tid = threadIdx.x;
    const int wave = tid >> 6, lane = tid & 63;
    float s0=0.f,s1=0.f,s2=0.f,s3=0.f,s4=0.f,s5=0.f;

    int tlimB = min(p.Fo, p.ofsplit[b]);
    int nCB = (tlimB + p.chunkB - 1) / p.chunkB;        // valid pass-B chunks
    for (int n = tid; n < p.Nh; n += 1024) {
        int par = 0;
        for (int c = 0; c < nCB; ++c)
            par += p.hitsB[((size_t)(c * p.B + b)) * p.Nh + n];
        bool ext = (par & 1) == 0;
        float val = 25.0f * tanhf(p.anchor_h[(size_t)b*p.Nh + n] / 25.0f);
        if (ext) { s0 += val; s1 += 1.0f; } else { s2 += val; s3 += 1.0f; }
    }
    int split = p.ovsplit[b];
    for (int m = tid; m < split; m += 1024) {
        int par = 0;
        for (int c = 0; c < p.CA; ++c)
            par += p.hitsA[((size_t)(c * p.B + b)) * p.No + m];
        if (par & 1) {                                   // interior & valid
            s4 += 25.0f * tanhf(p.anchor_o[(size_t)b*p.No + m] / 25.0f);
            s5 += 1.0f;
        }
    }
    for (int off = 32; off > 0; off >>= 1) {
        s0 += __shfl_xor(s0, off, 64);
        s1 += __shfl_xor(s1, off, 64);
        s2 += __shfl_xor(s2, off, 64);
        s3 += __shfl_xor(s3, off, 64);
        s4 += __shfl_xor(s4, off, 64);
        s5 += __shfl_xor(s5, off, 64);
    }
    __shared__ float red[16][6];
    __shared__ bool s_last;
    if (lane == 0) {
        red[wave][0]=s0; red[wave][1]=s1; red[wave][2]=s2;
        red[wave][3]=s3; red[wave][4]=s4; red[wave][5]=s5;
    }
    __syncthreads();
    if (tid == 0) {
        float t0=0.f,t1=0.f,t2=0.f,t3=0.f,t4=0.f,t5=0.f;
        for (int wv = 0; wv < 16; ++wv) {
            t0 += red[wv][0]; t1 += red[wv][1]; t2 += red[wv][2];
            t3 += red[wv][3]; t4 += red[wv][4]; t5 += red[wv][5];
        }
        p.out[2 + b]  = (t1 > 0.f) ? t0 / fmaxf(t1, 1.f) : 0.f;
        float ph      = (t3 > 0.f) ? t2 / fmaxf(t3, 1.f) : 0.f;
        float po      = (t5 > 0.f) ? t4 / fmaxf(t5, 1.f) : 0.f;
        p.out[10 + b] = ph + po;
        float* pp = p.partials + b * 6;
        pp[0]=t0; pp[1]=t1; pp[2]=t2; pp[3]=t3; pp[4]=t4; pp[5]=t5;
        __threadfence();                     // release partials
        unsigned int old = atomicAdd(p.done, 1u);
        s_last = (old == (unsigned int)(gridDim.x - 1));
    }
    __syncthreads();
    if (!s_last || tid != 0) return;
    __threadfence();                         // acquire others' partials
    float sm=0.f,cm=0.f,sph=0.f,cph=0.f,spo=0.f,cpo=0.f;
    for (int bb = 0; bb < p.B; ++bb) {
        const float* pp = p.partials + bb * 6;
        sm  += pp[0]; cm  += pp[1]; sph += pp[2];
        cph += pp[3]; spo += pp[4]; cpo += pp[5];
    }
    float missed = (cm  > 0.f) ? sm  / fmaxf(cm , 1.f) : 0.f;
    float ph     = (cph > 0.f) ? sph / fmaxf(cph, 1.f) : 0.f;
    float po     = (cpo > 0.f) ? spo / fmaxf(cpo, 1.f) : 0.f;
    p.out[0] = missed;
    p.out[1] = ph + po;
}

// ---------------------------------------------------------------------------
extern "C" void kernel_launch(void* const* d_in, const int* in_sizes, int n_in,
                              void* d_out, int out_size, void* d_ws, size_t ws_size,
                              hipStream_t stream) {
    Params p;
    p.hand_verts = (const float*)d_in[0];
    p.hand_faces = (const int*)d_in[1];
    p.obj_verts  = (const float*)d_in[2];
    p.obj_faces  = (const int*)d_in[3];
    p.ovsplit    = (const int*)d_in[4];
    p.ofsplit    = (const int*)d_in[5];
    p.out        = (float*)d_out;

    p.B  = in_sizes[4];
    p.Nh = in_sizes[0] / (3 * p.B);
    p.Fh = in_sizes[1] / (3 * p.B);
    p.No = in_sizes[2] / (3 * p.B);
    p.Fo = in_sizes[3] / (3 * p.B);

    p.CA = 16; p.CB = 32;
    p.chunkA = (p.Fh + p.CA - 1) / p.CA;       // 97  for Fh=1538 (388 f4 <= 512)
    p.chunkB = (p.Fo + p.CB - 1) / p.CB;       // 125 for Fo=4000 (500 f4 <= 512)
    p.pbA = (p.No + PTS_PER_BLK - 1) / PTS_PER_BLK;   // 4
    p.pbB = (p.Nh + PTS_PER_BLK - 1) / PTS_PER_BLK;   // 2
    p.blocksA = p.pbA * p.CA * p.B;            // 512
    p.blocksB = p.pbB * p.CB * p.B;            // 512

    char* ws = (char*)d_ws;
    size_t off = 0;
    auto alloc = [&](size_t bytes) -> void* {
        void* q = ws + off;
        off = (off + bytes + 255) & ~(size_t)255;
        return q;
    };
    p.hitsA    = (int*)   alloc((size_t)p.CA * p.B * p.No * sizeof(int));
    p.hitsB    = (int*)   alloc((size_t)p.CB * p.B * p.Nh * sizeof(int));
    p.anchor_h = (float*) alloc((size_t)p.B * p.Nh * sizeof(float));
    p.anchor_o = (float*) alloc((size_t)p.B * p.No * sizeof(float));
    p.partials = (float*) alloc((size_t)p.B * 6 * sizeof(float));
    p.done     = (unsigned int*)alloc(sizeof(unsigned int));

    int totalMin   = p.B * (p.Nh + p.No);
    int nMinBlocks = (totalMin + 3) / 4;       // 4 argmin waves per block
    int grid = p.blocksA + p.blocksB + nMinBlocks;

    mega<<<grid, 256, 0, stream>>>(p);
    reduce_fin<<<p.B, 1024, 0, stream>>>(p);
}